// Round 1
// baseline (444.834 us; speedup 1.0000x reference)
//
#include <hip/hip_runtime.h>
#include <math.h>

// Problem constants
#define BB   8
#define CIN  256
#define SS   1024      // H*W
#define NH   8
#define CHD  32
#define HIDC 256
#define QKVM 768

// ---------------------------------------------------------------------------
// Tiled fp32 GEMM: Y[b][o][s] = act( sum_c W[o][c] * X[b][c][s] + bias[o] ) (+skip)
// Tile: 64 (o) x 128 (s), BK=32. Block 256 threads; thread owns 8(o) x 4(s).
// ---------------------------------------------------------------------------
template<int M, int K, bool SILU, bool SKIP>
__global__ __launch_bounds__(256) void gemm_bias_act(
    const float* __restrict__ W, const float* __restrict__ X,
    const float* __restrict__ bias, const float* __restrict__ skip,
    float* __restrict__ Y)
{
    __shared__ __align__(16) float Ws[64][36];   // [o][k], padded
    __shared__ __align__(16) float Xs[32][132];  // [k][s], padded

    const int s0  = blockIdx.x * 128;
    const int o0  = blockIdx.y * 64;
    const int b   = blockIdx.z;
    const int tid = threadIdx.x;
    const int tx  = tid & 31;   // s group
    const int ty  = tid >> 5;   // o group

    const float* Xb = X + (size_t)b * K * SS;

    float acc[8][4];
    #pragma unroll
    for (int r = 0; r < 8; ++r)
        #pragma unroll
        for (int j = 0; j < 4; ++j) acc[r][j] = 0.f;

    for (int k0 = 0; k0 < K; k0 += 32) {
        // stage X tile [32][128] : 1024 float4, 4 per thread
        #pragma unroll
        for (int i = 0; i < 4; ++i) {
            int u  = tid + i * 256;
            int c  = u >> 5;
            int t4 = u & 31;
            float4 v = *(const float4*)(Xb + (size_t)(k0 + c) * SS + s0 + t4 * 4);
            *(float4*)&Xs[c][t4 * 4] = v;
        }
        // stage W tile [64][32] : 512 float4, 2 per thread
        #pragma unroll
        for (int i = 0; i < 2; ++i) {
            int u = tid + i * 256;
            int o = u >> 3;
            int j = u & 7;
            float4 v = *(const float4*)(W + (size_t)(o0 + o) * K + k0 + j * 4);
            *(float4*)&Ws[o][j * 4] = v;
        }
        __syncthreads();

        #pragma unroll
        for (int k4 = 0; k4 < 8; ++k4) {
            float4 xr[4];
            #pragma unroll
            for (int m = 0; m < 4; ++m)
                xr[m] = *(const float4*)&Xs[k4 * 4 + m][tx * 4];
            #pragma unroll
            for (int r = 0; r < 8; ++r) {
                float4 wr = *(const float4*)&Ws[ty * 8 + r][k4 * 4];
                float wa[4] = {wr.x, wr.y, wr.z, wr.w};
                #pragma unroll
                for (int m = 0; m < 4; ++m) {
                    float xa[4] = {xr[m].x, xr[m].y, xr[m].z, xr[m].w};
                    #pragma unroll
                    for (int j = 0; j < 4; ++j)
                        acc[r][j] += wa[m] * xa[j];
                }
            }
        }
        __syncthreads();
    }

    // epilogue
    #pragma unroll
    for (int r = 0; r < 8; ++r) {
        const int o = o0 + ty * 8 + r;
        const float bb = bias[o];
        size_t idx = (size_t)b * M * SS + (size_t)o * SS + s0 + tx * 4;
        float v[4];
        #pragma unroll
        for (int j = 0; j < 4; ++j) {
            float z = acc[r][j] + bb;
            if (SILU) z = z / (1.f + __expf(-z));
            v[j] = z;
        }
        if (SKIP) {
            float4 sk = *(const float4*)(skip + idx);
            v[0] += sk.x; v[1] += sk.y; v[2] += sk.z; v[3] += sk.w;
        }
        *(float4*)(Y + idx) = make_float4(v[0], v[1], v[2], v[3]);
    }
}

// ---------------------------------------------------------------------------
// Flash-style attention, fp32. One q-row per thread, online softmax.
// Head n of batch b uses qkv rows n*96+{0..31}=Q, +32..63=K, +64..95=V.
// attn_out[b][n*32+c][s] = sum_t softmax_t(q.k/sqrt(32)) * v[c][t]
// Grid: (64 bn, 4 qtiles), block 256.
// ---------------------------------------------------------------------------
__global__ __launch_bounds__(256) void attn_kernel(
    const float* __restrict__ qkv, float* __restrict__ attn_out)
{
    __shared__ __align__(16) float Ksh[32][128];   // [c][t]
    __shared__ __align__(16) float Vsh[32][128];   // [c][t]

    const int bn = blockIdx.x;           // 0..63
    const int b  = bn >> 3;
    const int n  = bn & 7;
    const int s  = blockIdx.y * 256 + threadIdx.x;

    const size_t base = ((size_t)b * QKVM + (size_t)n * 96) * SS;
    const float* Qp = qkv + base;             // 32 rows
    const float* Kp = qkv + base + 32 * SS;
    const float* Vp = qkv + base + 64 * SS;

    // q (scale folded in)
    float q[32];
    #pragma unroll
    for (int c = 0; c < 32; ++c)
        q[c] = Qp[(size_t)c * SS + s] * 0.17677669529663687f;  // 1/sqrt(32)

    float o_[32];
    #pragma unroll
    for (int c = 0; c < 32; ++c) o_[c] = 0.f;
    float m = -INFINITY;
    float l = 0.f;

    for (int t0 = 0; t0 < SS; t0 += 128) {
        __syncthreads();   // protect previous tile reads before overwrite
        #pragma unroll
        for (int i = 0; i < 4; ++i) {
            int u  = threadIdx.x + i * 256;   // 1024 float4 per tile
            int c  = u >> 5;
            int t4 = u & 31;
            *(float4*)&Ksh[c][t4 * 4] = *(const float4*)(Kp + (size_t)c * SS + t0 + t4 * 4);
            *(float4*)&Vsh[c][t4 * 4] = *(const float4*)(Vp + (size_t)c * SS + t0 + t4 * 4);
        }
        __syncthreads();

        for (int tc = 0; tc < 32; ++tc) {
            float s4[4] = {0.f, 0.f, 0.f, 0.f};
            #pragma unroll
            for (int c = 0; c < 32; ++c) {
                float4 k4 = *(const float4*)&Ksh[c][tc * 4];  // uniform -> broadcast
                s4[0] += q[c] * k4.x;
                s4[1] += q[c] * k4.y;
                s4[2] += q[c] * k4.z;
                s4[3] += q[c] * k4.w;
            }
            // online softmax update (chunk max first; rescale at most once)
            float cm = fmaxf(fmaxf(s4[0], s4[1]), fmaxf(s4[2], s4[3]));
            if (cm > m) {
                float sc = __expf(m - cm);   // expf(-inf)=0 handles first chunk
                l *= sc;
                #pragma unroll
                for (int c = 0; c < 32; ++c) o_[c] *= sc;
                m = cm;
            }
            float p4[4];
            #pragma unroll
            for (int j = 0; j < 4; ++j) {
                float p = __expf(s4[j] - m);
                l += p;
                p4[j] = p;
            }
            #pragma unroll
            for (int c = 0; c < 32; ++c) {
                float4 v4 = *(const float4*)&Vsh[c][tc * 4];  // uniform -> broadcast
                o_[c] += p4[0] * v4.x + p4[1] * v4.y + p4[2] * v4.z + p4[3] * v4.w;
            }
        }
    }

    const float inv_l = 1.f / l;
    const size_t obase = ((size_t)b * HIDC + (size_t)n * 32) * SS + s;
    #pragma unroll
    for (int c = 0; c < 32; ++c)
        attn_out[obase + (size_t)c * SS] = o_[c] * inv_l;
}

// ---------------------------------------------------------------------------
extern "C" void kernel_launch(void* const* d_in, const int* in_sizes, int n_in,
                              void* d_out, int out_size, void* d_ws, size_t ws_size,
                              hipStream_t stream)
{
    const float* x     = (const float*)d_in[0];  // [8][256][32][32]
    const float* w_qkv = (const float*)d_in[1];  // [768][256]
    const float* b_qkv = (const float*)d_in[2];  // [768]
    const float* w_out = (const float*)d_in[3];  // [256][256]
    const float* b_out = (const float*)d_in[4];  // [256]
    float* out = (float*)d_out;                  // [8][256][32][32]

    // workspace: qkv [8][768][1024] fp32 (25.2MB) + attn [8][256][1024] fp32 (8.4MB) = 32MB
    float* qkv_ws  = (float*)d_ws;
    float* attn_ws = qkv_ws + (size_t)BB * QKVM * SS;

    // 1) qkv = silu(W_qkv @ x + b_qkv)
    gemm_bias_act<QKVM, CIN, true, false>
        <<<dim3(SS / 128, QKVM / 64, BB), 256, 0, stream>>>(w_qkv, x, b_qkv, nullptr, qkv_ws);

    // 2) per-head attention
    attn_kernel<<<dim3(BB * NH, SS / 256), 256, 0, stream>>>(qkv_ws, attn_ws);

    // 3) out = W_out @ attn + b_out + x
    gemm_bias_act<CIN, HIDC, false, true>
        <<<dim3(SS / 128, CIN / 64, BB), 256, 0, stream>>>(w_out, attn_ws, b_out, x, out);
}

// Round 2
// 111.013 us; speedup vs baseline: 4.0071x; 4.0071x over previous
//
#include <hip/hip_runtime.h>
#include <math.h>

#define BB   8
#define NHD  8
#define SSZ  1024
#define CIN  256
#define HIDC 256

typedef __bf16 bf16_t;
typedef bf16_t bf16x8 __attribute__((ext_vector_type(8)));
typedef float  f32x4v __attribute__((ext_vector_type(4)));

__device__ inline unsigned cvt_pk_bf16(float lo, float hi) {
    unsigned r;
    asm("v_cvt_pk_bf16_f32 %0, %1, %2" : "=v"(r) : "v"(lo), "v"(hi));
    return r;
}
__device__ inline unsigned short f2bf(float f) {
    unsigned u = __builtin_bit_cast(unsigned, f);
    u = (u + 0x7fffu + ((u >> 16) & 1u)) >> 16;   // RNE
    return (unsigned short)u;
}

// ---------------------------------------------------------------------------
// QKV GEMM: one 32-channel part (q|k|v of one head) per block, 128 s cols.
// q/k parts -> transposed bf16 store qkT[bh][s][64] (slot-permuted, Q scaled).
// v part    -> bf16 store v_buf[bh][d][1024] (in-row 32-key slot permutation).
// slot(ch) = ((ch>>2)&3)*8 + ((ch>>4)&1)*4 + (ch&3)  — matches MFMA frag (g,e).
// ---------------------------------------------------------------------------
__global__ __launch_bounds__(256) void qkv_gemm(
    const float* __restrict__ W, const float* __restrict__ X,
    const float* __restrict__ bias,
    unsigned short* __restrict__ qkT, unsigned short* __restrict__ v_buf)
{
    __shared__ __align__(16) float Xs[32][132];
    __shared__ __align__(16) float Ws[32][36];
    __shared__ __align__(16) unsigned short Ts[128][34];

    const int tid = threadIdx.x;
    const int tx = tid & 31, ty = tid >> 5;
    const int s0 = blockIdx.x * 128;
    const int p  = blockIdx.y;          // 0..23 = head*3 + part
    const int b  = blockIdx.z;
    const int part = p % 3;             // 0=q 1=k 2=v
    const int n    = p / 3;
    const int o0   = p * 32;

    const float* Xb = X + (size_t)b * CIN * SSZ;

    float acc[4][4];
    #pragma unroll
    for (int r = 0; r < 4; ++r)
        #pragma unroll
        for (int j = 0; j < 4; ++j) acc[r][j] = 0.f;

    for (int k0 = 0; k0 < CIN; k0 += 32) {
        #pragma unroll
        for (int i = 0; i < 4; ++i) {
            int u = tid + i * 256;
            int c = u >> 5, t4 = u & 31;
            *(float4*)&Xs[c][t4 * 4] = *(const float4*)(Xb + (size_t)(k0 + c) * SSZ + s0 + t4 * 4);
        }
        {
            int o = tid >> 3, j = tid & 7;
            *(float4*)&Ws[o][j * 4] = *(const float4*)(W + (size_t)(o0 + o) * CIN + k0 + j * 4);
        }
        __syncthreads();
        #pragma unroll
        for (int k4 = 0; k4 < 8; ++k4) {
            float4 xr[4];
            #pragma unroll
            for (int m = 0; m < 4; ++m) xr[m] = *(const float4*)&Xs[k4 * 4 + m][tx * 4];
            #pragma unroll
            for (int r = 0; r < 4; ++r) {
                float4 wr = *(const float4*)&Ws[ty * 4 + r][k4 * 4];
                float wa[4] = {wr.x, wr.y, wr.z, wr.w};
                #pragma unroll
                for (int m = 0; m < 4; ++m) {
                    float xa[4] = {xr[m].x, xr[m].y, xr[m].z, xr[m].w};
                    #pragma unroll
                    for (int j = 0; j < 4; ++j) acc[r][j] += wa[m] * xa[j];
                }
            }
        }
        __syncthreads();
    }

    float vals[4][4];
    #pragma unroll
    for (int r = 0; r < 4; ++r) {
        const float bb = bias[o0 + ty * 4 + r];
        #pragma unroll
        for (int j = 0; j < 4; ++j) {
            float z = acc[r][j] + bb;
            z = z / (1.f + __expf(-z));                 // SiLU
            if (part == 0) z *= 0.17677669529663687f;   // 1/sqrt(32) folded into Q
            vals[r][j] = z;
        }
    }

    if (part == 2) {
        // V: coalesced bf16 store with in-row key permutation:
        // key s0+tx*4+j -> slot (tx&3)*8 + ((tx>>2)&1)*4 + j within its 32-block
        const size_t rowbase = (size_t)(b * NHD + n) * 32;
        const int off = s0 + (tx >> 3) * 32 + (tx & 3) * 8 + ((tx >> 2) & 1) * 4;
        #pragma unroll
        for (int r = 0; r < 4; ++r) {
            ushort4 pk;
            pk.x = f2bf(vals[r][0]); pk.y = f2bf(vals[r][1]);
            pk.z = f2bf(vals[r][2]); pk.w = f2bf(vals[r][3]);
            *(ushort4*)(v_buf + ((rowbase + ty * 4 + r) << 10) + off) = pk;
        }
        return;
    }

    // q/k: transpose through LDS, channel slot-permuted, then coalesced rows
    __syncthreads();
    #pragma unroll
    for (int r = 0; r < 4; ++r) {
        const int ch = ty * 4 + r;
        const int slot = ((ch >> 2) & 3) * 8 + ((ch >> 4) & 1) * 4 + (ch & 3);
        #pragma unroll
        for (int j = 0; j < 4; ++j)
            Ts[tx * 4 + j][slot] = f2bf(vals[r][j]);
    }
    __syncthreads();
    const int sl = tid >> 1, half = tid & 1;
    unsigned wv[8];
    #pragma unroll
    for (int i = 0; i < 8; ++i)
        wv[i] = *(const unsigned*)((const char*)&Ts[sl][0] + half * 32 + i * 4);
    unsigned short* dst = qkT + ((size_t)(b * NHD + n) << 16) + (size_t)(s0 + sl) * 64 + part * 32;
    *(uint4*)(dst)     = make_uint4(wv[0], wv[1], wv[2], wv[3]);
    *(uint4*)(dst + 8) = make_uint4(wv[4], wv[5], wv[6], wv[7]);
}

// ---------------------------------------------------------------------------
// MFMA flash attention. Swapped QK^T: S^T = mfma(A=K, B=Q) -> q = lane&15.
// P frags feed PV's B operand directly; V is the A operand (rows = d).
// No LDS, no barriers. Block = 4 waves x 32 q rows; grid = (64 heads, 8 qtiles).
// ---------------------------------------------------------------------------
__global__ __launch_bounds__(256) void attn_mfma(
    const unsigned short* __restrict__ qkT,
    const unsigned short* __restrict__ v_buf,
    float* __restrict__ attn_ws)
{
    const int tid = threadIdx.x;
    const int l   = tid & 63;
    const int w   = tid >> 6;
    const int g   = l >> 4;
    const int ln  = l & 15;
    const int bh  = blockIdx.x;          // 0..63
    const int qt  = blockIdx.y;          // 0..7

    const unsigned short* qkrow = qkT  + ((size_t)bh << 16);  // [1024][64]
    const unsigned short* vb    = v_buf + ((size_t)bh << 15); // [32][1024]

    const int q0 = qt * 128 + w * 32;

    bf16x8 qf_[2];
    #pragma unroll
    for (int qf = 0; qf < 2; ++qf)
        qf_[qf] = *(const bf16x8*)(qkrow + (size_t)(q0 + qf * 16 + ln) * 64 + g * 8);

    f32x4v O_[2][2];
    const f32x4v zero4 = {0.f, 0.f, 0.f, 0.f};
    #pragma unroll
    for (int df = 0; df < 2; ++df)
        #pragma unroll
        for (int qf = 0; qf < 2; ++qf) O_[df][qf] = zero4;
    float m_[2] = {-1e30f, -1e30f};
    float l_[2] = {0.f, 0.f};

    for (int t0 = 0; t0 < SSZ; t0 += 64) {
        bf16x8 kf_[4];
        #pragma unroll
        for (int kf = 0; kf < 4; ++kf)
            kf_[kf] = *(const bf16x8*)(qkrow + (size_t)(t0 + kf * 16 + ln) * 64 + 32 + g * 8);
        bf16x8 vf_[2][2];
        #pragma unroll
        for (int df = 0; df < 2; ++df)
            #pragma unroll
            for (int kb = 0; kb < 2; ++kb)
                vf_[df][kb] = *(const bf16x8*)(vb + ((size_t)(df * 16 + ln) << 10) + t0 + kb * 32 + g * 8);

        f32x4v s_[2][4];
        #pragma unroll
        for (int qf = 0; qf < 2; ++qf)
            #pragma unroll
            for (int kf = 0; kf < 4; ++kf)
                s_[qf][kf] = __builtin_amdgcn_mfma_f32_16x16x32_bf16(kf_[kf], qf_[qf], zero4, 0, 0, 0);

        #pragma unroll
        for (int qf = 0; qf < 2; ++qf) {
            float cmax = -1e30f;
            #pragma unroll
            for (int kf = 0; kf < 4; ++kf)
                #pragma unroll
                for (int r = 0; r < 4; ++r) cmax = fmaxf(cmax, s_[qf][kf][r]);
            cmax = fmaxf(cmax, __shfl_xor(cmax, 16));
            cmax = fmaxf(cmax, __shfl_xor(cmax, 32));
            const float mnew = fmaxf(m_[qf], cmax);
            const float corr = __expf(m_[qf] - mnew);
            float ssum = 0.f;
            #pragma unroll
            for (int kf = 0; kf < 4; ++kf)
                #pragma unroll
                for (int r = 0; r < 4; ++r) {
                    float pv = __expf(s_[qf][kf][r] - mnew);
                    s_[qf][kf][r] = pv;
                    ssum += pv;
                }
            ssum += __shfl_xor(ssum, 16);
            ssum += __shfl_xor(ssum, 32);
            l_[qf] = l_[qf] * corr + ssum;
            m_[qf] = mnew;
            #pragma unroll
            for (int df = 0; df < 2; ++df)
                #pragma unroll
                for (int r = 0; r < 4; ++r) O_[df][qf][r] *= corr;
            #pragma unroll
            for (int kb = 0; kb < 2; ++kb) {
                unsigned w0 = cvt_pk_bf16(s_[qf][2 * kb][0],     s_[qf][2 * kb][1]);
                unsigned w1 = cvt_pk_bf16(s_[qf][2 * kb][2],     s_[qf][2 * kb][3]);
                unsigned w2 = cvt_pk_bf16(s_[qf][2 * kb + 1][0], s_[qf][2 * kb + 1][1]);
                unsigned w3 = cvt_pk_bf16(s_[qf][2 * kb + 1][2], s_[qf][2 * kb + 1][3]);
                bf16x8 pf = __builtin_bit_cast(bf16x8, make_uint4(w0, w1, w2, w3));
                #pragma unroll
                for (int df = 0; df < 2; ++df)
                    O_[df][qf] = __builtin_amdgcn_mfma_f32_16x16x32_bf16(vf_[df][kb], pf, O_[df][qf], 0, 0, 0);
            }
        }
    }

    const int b = bh >> 3, n = bh & 7;
    #pragma unroll
    for (int qf = 0; qf < 2; ++qf) {
        const float inv = 1.f / l_[qf];
        const int qpos = q0 + qf * 16 + ln;
        #pragma unroll
        for (int df = 0; df < 2; ++df)
            #pragma unroll
            for (int r = 0; r < 4; ++r) {
                const int d = df * 16 + g * 4 + r;   // D row = (lane>>4)*4+reg [m89]
                attn_ws[((size_t)(b * HIDC + n * 32 + d) << 10) + qpos] = O_[df][qf][r] * inv;
            }
    }
}

// ---------------------------------------------------------------------------
// Out GEMM (fp32, unchanged structure): out = W_out @ attn + b_out + x
// ---------------------------------------------------------------------------
__global__ __launch_bounds__(256) void out_gemm(
    const float* __restrict__ W, const float* __restrict__ X,
    const float* __restrict__ bias, const float* __restrict__ skip,
    float* __restrict__ Y)
{
    __shared__ __align__(16) float Ws[64][36];
    __shared__ __align__(16) float Xs[32][132];

    const int s0  = blockIdx.x * 128;
    const int o0  = blockIdx.y * 64;
    const int b   = blockIdx.z;
    const int tid = threadIdx.x;
    const int tx  = tid & 31;
    const int ty  = tid >> 5;

    const float* Xb = X + (size_t)b * HIDC * SSZ;

    float acc[8][4];
    #pragma unroll
    for (int r = 0; r < 8; ++r)
        #pragma unroll
        for (int j = 0; j < 4; ++j) acc[r][j] = 0.f;

    for (int k0 = 0; k0 < HIDC; k0 += 32) {
        #pragma unroll
        for (int i = 0; i < 4; ++i) {
            int u = tid + i * 256;
            int c = u >> 5, t4 = u & 31;
            *(float4*)&Xs[c][t4 * 4] = *(const float4*)(Xb + (size_t)(k0 + c) * SSZ + s0 + t4 * 4);
        }
        #pragma unroll
        for (int i = 0; i < 2; ++i) {
            int u = tid + i * 256;
            int o = u >> 3, j = u & 7;
            *(float4*)&Ws[o][j * 4] = *(const float4*)(W + (size_t)(o0 + o) * HIDC + k0 + j * 4);
        }
        __syncthreads();
        #pragma unroll
        for (int k4 = 0; k4 < 8; ++k4) {
            float4 xr[4];
            #pragma unroll
            for (int m = 0; m < 4; ++m) xr[m] = *(const float4*)&Xs[k4 * 4 + m][tx * 4];
            #pragma unroll
            for (int r = 0; r < 8; ++r) {
                float4 wr = *(const float4*)&Ws[ty * 8 + r][k4 * 4];
                float wa[4] = {wr.x, wr.y, wr.z, wr.w};
                #pragma unroll
                for (int m = 0; m < 4; ++m) {
                    float xa[4] = {xr[m].x, xr[m].y, xr[m].z, xr[m].w};
                    #pragma unroll
                    for (int j = 0; j < 4; ++j) acc[r][j] += wa[m] * xa[j];
                }
            }
        }
        __syncthreads();
    }

    #pragma unroll
    for (int r = 0; r < 8; ++r) {
        const int o = o0 + ty * 8 + r;
        const float bb = bias[o];
        size_t idx = (size_t)b * CIN * SSZ + (size_t)o * SSZ + s0 + tx * 4;
        float4 sk = *(const float4*)(skip + idx);
        float4 v;
        v.x = acc[r][0] + bb + sk.x;
        v.y = acc[r][1] + bb + sk.y;
        v.z = acc[r][2] + bb + sk.z;
        v.w = acc[r][3] + bb + sk.w;
        *(float4*)(Y + idx) = v;
    }
}

// ---------------------------------------------------------------------------
extern "C" void kernel_launch(void* const* d_in, const int* in_sizes, int n_in,
                              void* d_out, int out_size, void* d_ws, size_t ws_size,
                              hipStream_t stream)
{
    const float* x     = (const float*)d_in[0];
    const float* w_qkv = (const float*)d_in[1];
    const float* b_qkv = (const float*)d_in[2];
    const float* w_out = (const float*)d_in[3];
    const float* b_out = (const float*)d_in[4];
    float* out = (float*)d_out;

    // ws: qkT bf16 [64][1024][64] (8.39MB) | v bf16 [64][32][1024] (4.19MB) | attn f32 [8][256][1024] (8.39MB)
    unsigned short* qkT   = (unsigned short*)d_ws;
    unsigned short* v_buf = qkT + ((size_t)64 << 16);
    float*          attn  = (float*)(v_buf + ((size_t)64 << 15));

    qkv_gemm<<<dim3(SSZ / 128, 24, BB), 256, 0, stream>>>(w_qkv, x, b_qkv, qkT, v_buf);
    attn_mfma<<<dim3(BB * NHD, SSZ / 128), 256, 0, stream>>>(qkT, v_buf, attn);
    out_gemm<<<dim3(SSZ / 128, CIN / 64, BB), 256, 0, stream>>>(w_out, attn, b_out, x, out);
}

// Round 3
// 74.194 us; speedup vs baseline: 5.9955x; 1.4962x over previous
//
#include <hip/hip_runtime.h>
#include <math.h>

#define BB   8
#define NHD  8
#define SSZ  1024
#define CIN  256
#define HIDC 256

typedef __bf16 bf16_t;
typedef bf16_t bf16x8 __attribute__((ext_vector_type(8)));
typedef float  f32x4v __attribute__((ext_vector_type(4)));

__device__ inline unsigned cvt_pk_bf16(float lo, float hi) {
    unsigned r;
    asm("v_cvt_pk_bf16_f32 %0, %1, %2" : "=v"(r) : "v"(lo), "v"(hi));
    return r;
}
__device__ inline unsigned short f2bf(float f) {
    unsigned u = __builtin_bit_cast(unsigned, f);
    u = (u + 0x7fffu + ((u >> 16) & 1u)) >> 16;   // RNE
    return (unsigned short)u;
}
// k-position map within a 32-block (consistent for all MFMA operand feeds)
__device__ inline int kmap5(int i) {
    return ((i >> 2) & 3) * 8 + ((i >> 4) & 1) * 4 + (i & 3);
}

// ---------------------------------------------------------------------------
// Prepass: z<8 -> transpose-convert x[b][c][s] f32 -> Xt[b][s][c] bf16 (64x64
// LDS tiles); z==8 -> convert w_qkv|w_out to bf16.
// ---------------------------------------------------------------------------
__global__ __launch_bounds__(256) void prepass(
    const float* __restrict__ x, const float* __restrict__ w_qkv,
    const float* __restrict__ w_out, unsigned short* __restrict__ Xt,
    unsigned short* __restrict__ Wq, unsigned short* __restrict__ Wo)
{
    const int tid = threadIdx.x;
    if (blockIdx.z == 8) {
        const int bid = blockIdx.y * 16 + blockIdx.x;       // 0..63
        const size_t base = (size_t)bid * 4096 + (size_t)tid * 16;
        #pragma unroll
        for (int i = 0; i < 4; ++i) {
            size_t idx = base + (size_t)i * 4;
            float4 v = (idx < 196608) ? *(const float4*)(w_qkv + idx)
                                      : *(const float4*)(w_out + (idx - 196608));
            ushort4 pk;
            pk.x = f2bf(v.x); pk.y = f2bf(v.y); pk.z = f2bf(v.z); pk.w = f2bf(v.w);
            if (idx < 196608) *(ushort4*)(Wq + idx) = pk;
            else              *(ushort4*)(Wo + (idx - 196608)) = pk;
        }
        return;
    }
    __shared__ unsigned short T[64][66];   // [s][c], pad 66 keeps b32 reads aligned
    const int b = blockIdx.z, c0 = blockIdx.y * 64, s0 = blockIdx.x * 64;
    const float* xb = x + ((size_t)b * CIN + c0) * SSZ + s0;
    #pragma unroll
    for (int i = 0; i < 4; ++i) {
        int u = tid + i * 256;              // 1024 float4 (64c x 16)
        int c = u >> 4, s4 = u & 15;
        float4 v = *(const float4*)(xb + (size_t)c * SSZ + s4 * 4);
        T[s4 * 4 + 0][c] = f2bf(v.x);
        T[s4 * 4 + 1][c] = f2bf(v.y);
        T[s4 * 4 + 2][c] = f2bf(v.z);
        T[s4 * 4 + 3][c] = f2bf(v.w);
    }
    __syncthreads();
    unsigned short* dst = Xt + ((size_t)b << 18) + (size_t)s0 * 256 + c0;
    #pragma unroll
    for (int i = 0; i < 2; ++i) {
        int u = tid + i * 256;              // 512 x (8 bf16 words)
        int s = u >> 3, c8 = u & 7;
        const unsigned* src = (const unsigned*)((const char*)&T[0][0] + s * 132 + c8 * 16);
        uint4 v = make_uint4(src[0], src[1], src[2], src[3]);
        *(uint4*)(dst + (size_t)s * 256 + c8 * 8) = v;
    }
}

// ---------------------------------------------------------------------------
// QKV GEMM via MFMA, LDS-free. Block = 4 waves (2o x 2s), tile 64o x 128s.
// Epilogue: bias+SiLU, then slot-permuted stores to qkT / v_buf (round-1 fmt).
// ---------------------------------------------------------------------------
__global__ __launch_bounds__(256) void qkv_mfma(
    const unsigned short* __restrict__ Wq, const unsigned short* __restrict__ Xt,
    const float* __restrict__ bias,
    unsigned short* __restrict__ qkT, unsigned short* __restrict__ v_buf)
{
    const int tid = threadIdx.x;
    const int l = tid & 63, w = tid >> 6;
    const int g = l >> 4, ln = l & 15;
    const int b  = blockIdx.z;
    const int ob = blockIdx.y * 64 + (w >> 1) * 32;
    const int sb = blockIdx.x * 128 + (w & 1) * 64;

    const unsigned short* Xb = Xt + ((size_t)b << 18);

    f32x4v acc[2][4];
    const f32x4v zero4 = {0.f, 0.f, 0.f, 0.f};
    #pragma unroll
    for (int df = 0; df < 2; ++df)
        #pragma unroll
        for (int sf = 0; sf < 4; ++sf) acc[df][sf] = zero4;

    #pragma unroll 2
    for (int k0 = 0; k0 < CIN; k0 += 32) {
        bf16x8 wf[2], xf[4];
        #pragma unroll
        for (int df = 0; df < 2; ++df)
            wf[df] = *(const bf16x8*)(Wq + (size_t)(ob + df * 16 + ln) * 256 + k0 + g * 8);
        #pragma unroll
        for (int sf = 0; sf < 4; ++sf)
            xf[sf] = *(const bf16x8*)(Xb + (size_t)(sb + sf * 16 + ln) * 256 + k0 + g * 8);
        #pragma unroll
        for (int df = 0; df < 2; ++df)
            #pragma unroll
            for (int sf = 0; sf < 4; ++sf)
                acc[df][sf] = __builtin_amdgcn_mfma_f32_16x16x32_bf16(wf[df], xf[sf], acc[df][sf], 0, 0, 0);
    }

    #pragma unroll
    for (int df = 0; df < 2; ++df) {
        const int o16  = ob + df * 16;
        const int part = (o16 >> 5) % 3;        // 0=q 1=k 2=v (parts are 32-aligned)
        const int head = o16 / 96;
        const int bh   = b * NHD + head;
        const float4 b4 = *(const float4*)(bias + o16 + g * 4);
        const float bias_r[4] = {b4.x, b4.y, b4.z, b4.w};
        const int chb = (o16 & 31) + g * 4;     // channel base for this lane's 4 regs

        float vals[4][4];
        #pragma unroll
        for (int sf = 0; sf < 4; ++sf)
            #pragma unroll
            for (int r = 0; r < 4; ++r) {
                float z = acc[df][sf][r] + bias_r[r];
                z = z / (1.f + __expf(-z));                 // SiLU
                if (part == 0) z *= 0.17677669529663687f;   // fold 1/sqrt(32) into Q
                vals[sf][r] = z;
            }

        if (part < 2) {
            const int slotb = ((chb >> 2) & 3) * 8 + ((chb >> 4) & 1) * 4;
            #pragma unroll
            for (int sf = 0; sf < 4; ++sf) {
                const int key = sb + sf * 16 + ln;
                ushort4 pk;
                pk.x = f2bf(vals[sf][0]); pk.y = f2bf(vals[sf][1]);
                pk.z = f2bf(vals[sf][2]); pk.w = f2bf(vals[sf][3]);
                *(ushort4*)(qkT + ((size_t)bh << 16) + (size_t)key * 64 + part * 32 + slotb) = pk;
            }
        } else {
            #pragma unroll
            for (int sf = 0; sf < 4; ++sf) {
                const int key  = sb + sf * 16 + ln;
                const int koff = (key & ~31) + kmap5(key & 31);
                #pragma unroll
                for (int r = 0; r < 4; ++r)
                    v_buf[((size_t)bh << 15) + ((size_t)(chb + r) << 10) + koff] = f2bf(vals[sf][r]);
            }
        }
    }
}

// ---------------------------------------------------------------------------
// MFMA flash attention (round-1 structure). Output now bf16 At[b][s][h].
// ---------------------------------------------------------------------------
__global__ __launch_bounds__(256) void attn_mfma(
    const unsigned short* __restrict__ qkT,
    const unsigned short* __restrict__ v_buf,
    unsigned short* __restrict__ At)
{
    const int tid = threadIdx.x;
    const int l   = tid & 63;
    const int w   = tid >> 6;
    const int g   = l >> 4;
    const int ln  = l & 15;
    const int bh  = blockIdx.x;
    const int qt  = blockIdx.y;

    const unsigned short* qkrow = qkT   + ((size_t)bh << 16);
    const unsigned short* vb    = v_buf + ((size_t)bh << 15);

    const int q0 = qt * 128 + w * 32;

    bf16x8 qf_[2];
    #pragma unroll
    for (int qf = 0; qf < 2; ++qf)
        qf_[qf] = *(const bf16x8*)(qkrow + (size_t)(q0 + qf * 16 + ln) * 64 + g * 8);

    f32x4v O_[2][2];
    const f32x4v zero4 = {0.f, 0.f, 0.f, 0.f};
    #pragma unroll
    for (int df = 0; df < 2; ++df)
        #pragma unroll
        for (int qf = 0; qf < 2; ++qf) O_[df][qf] = zero4;
    float m_[2] = {-1e30f, -1e30f};
    float l_[2] = {0.f, 0.f};

    for (int t0 = 0; t0 < SSZ; t0 += 64) {
        bf16x8 kf_[4];
        #pragma unroll
        for (int kf = 0; kf < 4; ++kf)
            kf_[kf] = *(const bf16x8*)(qkrow + (size_t)(t0 + kf * 16 + ln) * 64 + 32 + g * 8);
        bf16x8 vf_[2][2];
        #pragma unroll
        for (int df = 0; df < 2; ++df)
            #pragma unroll
            for (int kb = 0; kb < 2; ++kb)
                vf_[df][kb] = *(const bf16x8*)(vb + ((size_t)(df * 16 + ln) << 10) + t0 + kb * 32 + g * 8);

        f32x4v s_[2][4];
        #pragma unroll
        for (int qf = 0; qf < 2; ++qf)
            #pragma unroll
            for (int kf = 0; kf < 4; ++kf)
                s_[qf][kf] = __builtin_amdgcn_mfma_f32_16x16x32_bf16(kf_[kf], qf_[qf], zero4, 0, 0, 0);

        #pragma unroll
        for (int qf = 0; qf < 2; ++qf) {
            float cmax = -1e30f;
            #pragma unroll
            for (int kf = 0; kf < 4; ++kf)
                #pragma unroll
                for (int r = 0; r < 4; ++r) cmax = fmaxf(cmax, s_[qf][kf][r]);
            cmax = fmaxf(cmax, __shfl_xor(cmax, 16));
            cmax = fmaxf(cmax, __shfl_xor(cmax, 32));
            const float mnew = fmaxf(m_[qf], cmax);
            const float corr = __expf(m_[qf] - mnew);
            float ssum = 0.f;
            #pragma unroll
            for (int kf = 0; kf < 4; ++kf)
                #pragma unroll
                for (int r = 0; r < 4; ++r) {
                    float pv = __expf(s_[qf][kf][r] - mnew);
                    s_[qf][kf][r] = pv;
                    ssum += pv;
                }
            ssum += __shfl_xor(ssum, 16);
            ssum += __shfl_xor(ssum, 32);
            l_[qf] = l_[qf] * corr + ssum;
            m_[qf] = mnew;
            #pragma unroll
            for (int df = 0; df < 2; ++df)
                #pragma unroll
                for (int r = 0; r < 4; ++r) O_[df][qf][r] *= corr;
            #pragma unroll
            for (int kb = 0; kb < 2; ++kb) {
                unsigned w0 = cvt_pk_bf16(s_[qf][2 * kb][0],     s_[qf][2 * kb][1]);
                unsigned w1 = cvt_pk_bf16(s_[qf][2 * kb][2],     s_[qf][2 * kb][3]);
                unsigned w2 = cvt_pk_bf16(s_[qf][2 * kb + 1][0], s_[qf][2 * kb + 1][1]);
                unsigned w3 = cvt_pk_bf16(s_[qf][2 * kb + 1][2], s_[qf][2 * kb + 1][3]);
                bf16x8 pf = __builtin_bit_cast(bf16x8, make_uint4(w0, w1, w2, w3));
                #pragma unroll
                for (int df = 0; df < 2; ++df)
                    O_[df][qf] = __builtin_amdgcn_mfma_f32_16x16x32_bf16(vf_[df][kb], pf, O_[df][qf], 0, 0, 0);
            }
        }
    }

    const int b = bh >> 3, n = bh & 7;
    unsigned short* Ab = At + ((size_t)b << 18);
    #pragma unroll
    for (int qf = 0; qf < 2; ++qf) {
        const float inv = 1.f / l_[qf];
        const int qpos = q0 + qf * 16 + ln;
        #pragma unroll
        for (int df = 0; df < 2; ++df) {
            ushort4 pk;
            pk.x = f2bf(O_[df][qf][0] * inv);
            pk.y = f2bf(O_[df][qf][1] * inv);
            pk.z = f2bf(O_[df][qf][2] * inv);
            pk.w = f2bf(O_[df][qf][3] * inv);
            *(ushort4*)(Ab + (size_t)qpos * 256 + n * 32 + df * 16 + g * 4) = pk;
        }
    }
}

// ---------------------------------------------------------------------------
// Out GEMM via MFMA: out = Wo @ At^T + bias + x.  Block = 4 waves over s,
// tile 32o x 128s; wave = 32o x 32s.
// ---------------------------------------------------------------------------
__global__ __launch_bounds__(256) void out_mfma(
    const unsigned short* __restrict__ Wo, const unsigned short* __restrict__ At,
    const float* __restrict__ bias, const float* __restrict__ x,
    float* __restrict__ out)
{
    const int tid = threadIdx.x;
    const int l = tid & 63, w = tid >> 6;
    const int g = l >> 4, ln = l & 15;
    const int b  = blockIdx.z;
    const int ob = blockIdx.y * 32;
    const int sb = blockIdx.x * 128 + w * 32;

    const unsigned short* Ab = At + ((size_t)b << 18);

    f32x4v acc[2][2];
    const f32x4v zero4 = {0.f, 0.f, 0.f, 0.f};
    #pragma unroll
    for (int df = 0; df < 2; ++df)
        #pragma unroll
        for (int sf = 0; sf < 2; ++sf) acc[df][sf] = zero4;

    #pragma unroll 2
    for (int k0 = 0; k0 < HIDC; k0 += 32) {
        bf16x8 wf[2], af[2];
        #pragma unroll
        for (int df = 0; df < 2; ++df)
            wf[df] = *(const bf16x8*)(Wo + (size_t)(ob + df * 16 + ln) * 256 + k0 + g * 8);
        #pragma unroll
        for (int sf = 0; sf < 2; ++sf)
            af[sf] = *(const bf16x8*)(Ab + (size_t)(sb + sf * 16 + ln) * 256 + k0 + g * 8);
        #pragma unroll
        for (int df = 0; df < 2; ++df)
            #pragma unroll
            for (int sf = 0; sf < 2; ++sf)
                acc[df][sf] = __builtin_amdgcn_mfma_f32_16x16x32_bf16(wf[df], af[sf], acc[df][sf], 0, 0, 0);
    }

    #pragma unroll
    for (int df = 0; df < 2; ++df) {
        const float4 b4 = *(const float4*)(bias + ob + df * 16 + g * 4);
        const float bias_r[4] = {b4.x, b4.y, b4.z, b4.w};
        #pragma unroll
        for (int sf = 0; sf < 2; ++sf) {
            const int s = sb + sf * 16 + ln;
            #pragma unroll
            for (int r = 0; r < 4; ++r) {
                const int o = ob + df * 16 + g * 4 + r;
                const size_t idx = ((size_t)b * CIN + o) * SSZ + s;
                out[idx] = acc[df][sf][r] + bias_r[r] + x[idx];
            }
        }
    }
}

// ---------------------------------------------------------------------------
extern "C" void kernel_launch(void* const* d_in, const int* in_sizes, int n_in,
                              void* d_out, int out_size, void* d_ws, size_t ws_size,
                              hipStream_t stream)
{
    const float* x     = (const float*)d_in[0];
    const float* w_qkv = (const float*)d_in[1];
    const float* b_qkv = (const float*)d_in[2];
    const float* w_out = (const float*)d_in[3];
    const float* b_out = (const float*)d_in[4];
    float* out = (float*)d_out;

    // ws (u16 units): qkT 64<<16 | v_buf 64<<15 | Xt 8<<18 | At 8<<18 | Wq | Wo
    unsigned short* qkT   = (unsigned short*)d_ws;
    unsigned short* v_buf = qkT   + ((size_t)64 << 16);
    unsigned short* Xt    = v_buf + ((size_t)64 << 15);
    unsigned short* At    = Xt    + ((size_t)8 << 18);
    unsigned short* Wq    = At    + ((size_t)8 << 18);
    unsigned short* Wo    = Wq    + (size_t)768 * 256;

    prepass  <<<dim3(16, 4, 9),  256, 0, stream>>>(x, w_qkv, w_out, Xt, Wq, Wo);
    qkv_mfma <<<dim3(8, 12, 8),  256, 0, stream>>>(Wq, Xt, b_qkv, qkT, v_buf);
    attn_mfma<<<dim3(64, 8),     256, 0, stream>>>(qkT, v_buf, At);
    out_mfma <<<dim3(8, 8, 8),   256, 0, stream>>>(Wo, At, b_out, x, out);
}

// Round 4
// 63.318 us; speedup vs baseline: 7.0254x; 1.1718x over previous
//
#include <hip/hip_runtime.h>
#include <math.h>

#define BB   8
#define NHD  8
#define SSZ  1024
#define CIN  256
#define HIDC 256

typedef __bf16 bf16_t;
typedef bf16_t bf16x8 __attribute__((ext_vector_type(8)));
typedef float  f32x4v __attribute__((ext_vector_type(4)));

typedef __attribute__((address_space(3))) unsigned short as3_u16;
typedef __attribute__((address_space(1))) unsigned short as1_u16;

__device__ inline unsigned cvt_pk_bf16(float lo, float hi) {
    unsigned r;
    asm("v_cvt_pk_bf16_f32 %0, %1, %2" : "=v"(r) : "v"(lo), "v"(hi));
    return r;
}
__device__ inline unsigned short f2bf(float f) {
    unsigned u = __builtin_bit_cast(unsigned, f);
    u = (u + 0x7fffu + ((u >> 16) & 1u)) >> 16;   // RNE
    return (unsigned short)u;
}
__device__ inline float exp2_fast(float x) {     // v_exp_f32 IS 2^x
    float r;
    asm("v_exp_f32 %0, %1" : "=v"(r) : "v"(x));
    return r;
}
__device__ inline float fmax3(float a, float b, float c) {
    return fmaxf(fmaxf(a, b), c);                // clang fuses to v_max3_f32
}
__device__ inline int kmap5(int i) {
    return ((i >> 2) & 3) * 8 + ((i >> 4) & 1) * 4 + (i & 3);
}

// ---------------------------------------------------------------------------
// Prepass: z<8 -> transpose-convert x[b][c][s] f32 -> Xt[b][s][c] bf16;
// z==8 -> convert w_qkv|w_out to bf16.
// ---------------------------------------------------------------------------
__global__ __launch_bounds__(256) void prepass(
    const float* __restrict__ x, const float* __restrict__ w_qkv,
    const float* __restrict__ w_out, unsigned short* __restrict__ Xt,
    unsigned short* __restrict__ Wq, unsigned short* __restrict__ Wo)
{
    const int tid = threadIdx.x;
    if (blockIdx.z == 8) {
        const int bid = blockIdx.y * 16 + blockIdx.x;
        const size_t base = (size_t)bid * 4096 + (size_t)tid * 16;
        #pragma unroll
        for (int i = 0; i < 4; ++i) {
            size_t idx = base + (size_t)i * 4;
            float4 v = (idx < 196608) ? *(const float4*)(w_qkv + idx)
                                      : *(const float4*)(w_out + (idx - 196608));
            ushort4 pk;
            pk.x = f2bf(v.x); pk.y = f2bf(v.y); pk.z = f2bf(v.z); pk.w = f2bf(v.w);
            if (idx < 196608) *(ushort4*)(Wq + idx) = pk;
            else              *(ushort4*)(Wo + (idx - 196608)) = pk;
        }
        return;
    }
    __shared__ unsigned short T[64][66];
    const int b = blockIdx.z, c0 = blockIdx.y * 64, s0 = blockIdx.x * 64;
    const float* xb = x + ((size_t)b * CIN + c0) * SSZ + s0;
    #pragma unroll
    for (int i = 0; i < 4; ++i) {
        int u = tid + i * 256;
        int c = u >> 4, s4 = u & 15;
        float4 v = *(const float4*)(xb + (size_t)c * SSZ + s4 * 4);
        T[s4 * 4 + 0][c] = f2bf(v.x);
        T[s4 * 4 + 1][c] = f2bf(v.y);
        T[s4 * 4 + 2][c] = f2bf(v.z);
        T[s4 * 4 + 3][c] = f2bf(v.w);
    }
    __syncthreads();
    unsigned short* dst = Xt + ((size_t)b << 18) + (size_t)s0 * 256 + c0;
    #pragma unroll
    for (int i = 0; i < 2; ++i) {
        int u = tid + i * 256;
        int s = u >> 3, c8 = u & 7;
        const unsigned* src = (const unsigned*)((const char*)&T[0][0] + s * 132 + c8 * 16);
        uint4 v = make_uint4(src[0], src[1], src[2], src[3]);
        *(uint4*)(dst + (size_t)s * 256 + c8 * 8) = v;
    }
}

// ---------------------------------------------------------------------------
// QKV GEMM via MFMA, LDS-free, register double-buffer prefetch.
// Q is pre-scaled by log2(e)/sqrt(32) so attention softmax runs in exp2 domain.
// ---------------------------------------------------------------------------
#define QKV_LOAD(WF, XF, KK)                                                        \
    {                                                                               \
        _Pragma("unroll") for (int df = 0; df < 2; ++df)                            \
            WF[df] = *(const bf16x8*)(Wq + (size_t)(ob + df * 16 + ln) * 256 + (KK) + g * 8); \
        _Pragma("unroll") for (int sf = 0; sf < 4; ++sf)                            \
            XF[sf] = *(const bf16x8*)(Xb + (size_t)(sb + sf * 16 + ln) * 256 + (KK) + g * 8); \
    }
#define QKV_MMA(WF, XF)                                                             \
    {                                                                               \
        _Pragma("unroll") for (int df = 0; df < 2; ++df)                            \
            _Pragma("unroll") for (int sf = 0; sf < 4; ++sf)                        \
                acc[df][sf] = __builtin_amdgcn_mfma_f32_16x16x32_bf16(WF[df], XF[sf], acc[df][sf], 0, 0, 0); \
    }

__global__ __launch_bounds__(256) void qkv_mfma(
    const unsigned short* __restrict__ Wq, const unsigned short* __restrict__ Xt,
    const float* __restrict__ bias,
    unsigned short* __restrict__ qkT, unsigned short* __restrict__ v_buf)
{
    const int tid = threadIdx.x;
    const int l = tid & 63, w = tid >> 6;
    const int g = l >> 4, ln = l & 15;
    const int b  = blockIdx.z;
    const int ob = blockIdx.y * 64 + (w >> 1) * 32;
    const int sb = blockIdx.x * 128 + (w & 1) * 64;

    const unsigned short* Xb = Xt + ((size_t)b << 18);

    f32x4v acc[2][4];
    const f32x4v zero4 = {0.f, 0.f, 0.f, 0.f};
    #pragma unroll
    for (int df = 0; df < 2; ++df)
        #pragma unroll
        for (int sf = 0; sf < 4; ++sf) acc[df][sf] = zero4;

    bf16x8 wA[2], xA[4], wB[2], xB[4];
    QKV_LOAD(wA, xA, 0);
    #pragma unroll
    for (int k0 = 0; k0 < 256; k0 += 64) {
        if (k0 + 32 < 256) QKV_LOAD(wB, xB, k0 + 32);
        QKV_MMA(wA, xA);
        if (k0 + 64 < 256) QKV_LOAD(wA, xA, k0 + 64);
        QKV_MMA(wB, xB);
    }

    #pragma unroll
    for (int df = 0; df < 2; ++df) {
        const int o16  = ob + df * 16;
        const int part = (o16 >> 5) % 3;
        const int head = o16 / 96;
        const int bh   = b * NHD + head;
        const float4 b4 = *(const float4*)(bias + o16 + g * 4);
        const float bias_r[4] = {b4.x, b4.y, b4.z, b4.w};
        const int chb = (o16 & 31) + g * 4;

        float vals[4][4];
        #pragma unroll
        for (int sf = 0; sf < 4; ++sf)
            #pragma unroll
            for (int r = 0; r < 4; ++r) {
                float z = acc[df][sf][r] + bias_r[r];
                z = z / (1.f + __expf(-z));                  // SiLU
                if (part == 0) z *= 0.25503482107810536f;    // log2e/sqrt(32)
                vals[sf][r] = z;
            }

        if (part < 2) {
            const int slotb = ((chb >> 2) & 3) * 8 + ((chb >> 4) & 1) * 4;
            #pragma unroll
            for (int sf = 0; sf < 4; ++sf) {
                const int key = sb + sf * 16 + ln;
                ushort4 pk;
                pk.x = f2bf(vals[sf][0]); pk.y = f2bf(vals[sf][1]);
                pk.z = f2bf(vals[sf][2]); pk.w = f2bf(vals[sf][3]);
                *(ushort4*)(qkT + ((size_t)bh << 16) + (size_t)key * 64 + part * 32 + slotb) = pk;
            }
        } else {
            #pragma unroll
            for (int sf = 0; sf < 4; ++sf) {
                const int key  = sb + sf * 16 + ln;
                const int koff = (key & ~31) + kmap5(key & 31);
                #pragma unroll
                for (int r = 0; r < 4; ++r)
                    v_buf[((size_t)bh << 15) + ((size_t)(chb + r) << 10) + koff] = f2bf(vals[sf][r]);
            }
        }
    }
}

// ---------------------------------------------------------------------------
// MFMA flash attention with LDS K/V staging (double-buffered, raw barriers,
// counted vmcnt), exp2-domain softmax, defer-max, MFMA l-sum.
// Block = 4 waves x 32 q rows; grid = (64 heads, 8 qtiles).
// ---------------------------------------------------------------------------
__global__ __launch_bounds__(256) void attn_mfma(
    const unsigned short* __restrict__ qkT,
    const unsigned short* __restrict__ v_buf,
    unsigned short* __restrict__ At)
{
    __shared__ unsigned short Ksh[2][2048];   // [64 keys][32 ch], 64B rows, swizzled
    __shared__ unsigned short Vsh[2][2048];   // [32 d][64 keys], 128B rows, swizzled

    const int tid = threadIdx.x;
    const int l   = tid & 63;
    const int w   = tid >> 6;
    const int g   = l >> 4;
    const int ln  = l & 15;
    const int bh  = blockIdx.x;
    const int qt  = blockIdx.y;

    const unsigned short* qkrow = qkT   + ((size_t)bh << 16);
    const unsigned short* vb    = v_buf + ((size_t)bh << 15);

    const int q0 = qt * 128 + w * 32;

    bf16x8 qf_[2];
    #pragma unroll
    for (int qf = 0; qf < 2; ++qf)
        qf_[qf] = *(const bf16x8*)(qkrow + (size_t)(q0 + qf * 16 + ln) * 64 + g * 8);

    const bf16x8 ones = __builtin_bit_cast(bf16x8,
        make_uint4(0x3F803F80u, 0x3F803F80u, 0x3F803F80u, 0x3F803F80u));

    f32x4v O_[2][2], lacc[2];
    const f32x4v zero4 = {0.f, 0.f, 0.f, 0.f};
    #pragma unroll
    for (int df = 0; df < 2; ++df)
        #pragma unroll
        for (int qf = 0; qf < 2; ++qf) O_[df][qf] = zero4;
    lacc[0] = zero4; lacc[1] = zero4;
    float m_[2] = {-1e30f, -1e30f};

    // staging addresses (per-thread constant except t0)
    const int krow = tid >> 2, ksl = tid & 3;
    const int vrow = tid >> 3, vsl = tid & 7;
    const unsigned short* gk_base = qkrow + (size_t)krow * 64 + 32 + ((ksl ^ ((krow >> 1) & 3)) << 3);
    const unsigned short* gv_base = vb + ((size_t)vrow << 10) + ((vsl ^ (vrow & 7)) << 3);
    const int wbase = w << 9;   // wave-uniform LDS chunk (u16 units)

#define STAGE_KV(BUF, T0)                                                          \
    {                                                                              \
        __builtin_amdgcn_global_load_lds((const as1_u16*)(gk_base + (size_t)(T0) * 64), \
                                         (as3_u16*)&Ksh[BUF][wbase], 16, 0, 0);    \
        __builtin_amdgcn_global_load_lds((const as1_u16*)(gv_base + (T0)),         \
                                         (as3_u16*)&Vsh[BUF][wbase], 16, 0, 0);    \
    }

    auto compute = [&](int cur) {
        const unsigned short* Kb = &Ksh[cur][0];
        const unsigned short* Vb = &Vsh[cur][0];
        bf16x8 kf_[4], vf_[2][2];
        #pragma unroll
        for (int kf = 0; kf < 4; ++kf)
            kf_[kf] = *(const bf16x8*)(Kb + ((kf * 16 + ln) << 5) + ((g ^ ((ln >> 1) & 3)) << 3));
        #pragma unroll
        for (int df = 0; df < 2; ++df)
            #pragma unroll
            for (int kb = 0; kb < 2; ++kb)
                vf_[df][kb] = *(const bf16x8*)(Vb + ((df * 16 + ln) << 6) + ((((kb << 2) + g) ^ (ln & 7)) << 3));

        f32x4v s_[2][4];
        __builtin_amdgcn_s_setprio(1);
        #pragma unroll
        for (int qf = 0; qf < 2; ++qf)
            #pragma unroll
            for (int kf = 0; kf < 4; ++kf)
                s_[qf][kf] = __builtin_amdgcn_mfma_f32_16x16x32_bf16(kf_[kf], qf_[qf], zero4, 0, 0, 0);
        __builtin_amdgcn_s_setprio(0);

        #pragma unroll
        for (int qf = 0; qf < 2; ++qf) {
            float cmax = fmax3(s_[qf][0][0], s_[qf][0][1], s_[qf][0][2]);
            cmax = fmax3(cmax, s_[qf][0][3], s_[qf][1][0]);
            cmax = fmax3(cmax, s_[qf][1][1], s_[qf][1][2]);
            cmax = fmax3(cmax, s_[qf][1][3], s_[qf][2][0]);
            cmax = fmax3(cmax, s_[qf][2][1], s_[qf][2][2]);
            cmax = fmax3(cmax, s_[qf][2][3], s_[qf][3][0]);
            cmax = fmax3(cmax, s_[qf][3][1], s_[qf][3][2]);
            cmax = fmaxf(cmax, s_[qf][3][3]);
            cmax = fmaxf(cmax, __shfl_xor(cmax, 16));
            cmax = fmaxf(cmax, __shfl_xor(cmax, 32));

            if (__any(cmax > m_[qf] + 10.0f)) {           // defer-max (T13), log2 dom
                const float mnew = fmaxf(m_[qf], cmax);
                const float corr = exp2_fast(m_[qf] - mnew);
                #pragma unroll
                for (int df = 0; df < 2; ++df)
                    #pragma unroll
                    for (int r = 0; r < 4; ++r) O_[df][qf][r] *= corr;
                #pragma unroll
                for (int r = 0; r < 4; ++r) lacc[qf][r] *= corr;
                m_[qf] = mnew;
            }
            const float mm = m_[qf];
            #pragma unroll
            for (int kf = 0; kf < 4; ++kf)
                #pragma unroll
                for (int r = 0; r < 4; ++r)
                    s_[qf][kf][r] = exp2_fast(s_[qf][kf][r] - mm);

            __builtin_amdgcn_s_setprio(1);
            #pragma unroll
            for (int kb = 0; kb < 2; ++kb) {
                unsigned w0 = cvt_pk_bf16(s_[qf][2 * kb][0],     s_[qf][2 * kb][1]);
                unsigned w1 = cvt_pk_bf16(s_[qf][2 * kb][2],     s_[qf][2 * kb][3]);
                unsigned w2 = cvt_pk_bf16(s_[qf][2 * kb + 1][0], s_[qf][2 * kb + 1][1]);
                unsigned w3 = cvt_pk_bf16(s_[qf][2 * kb + 1][2], s_[qf][2 * kb + 1][3]);
                bf16x8 pf = __builtin_bit_cast(bf16x8, make_uint4(w0, w1, w2, w3));
                lacc[qf] = __builtin_amdgcn_mfma_f32_16x16x32_bf16(ones, pf, lacc[qf], 0, 0, 0);
                #pragma unroll
                for (int df = 0; df < 2; ++df)
                    O_[df][qf] = __builtin_amdgcn_mfma_f32_16x16x32_bf16(vf_[df][kb], pf, O_[df][qf], 0, 0, 0);
            }
            __builtin_amdgcn_s_setprio(0);
        }
    };

    STAGE_KV(0, 0);
    int cur = 0;
    for (int t = 0; t < 15; ++t) {
        STAGE_KV(cur ^ 1, (t + 1) * 64);
        asm volatile("s_waitcnt vmcnt(2)" ::: "memory");   // current tile landed
        __builtin_amdgcn_s_barrier();
        asm volatile("" ::: "memory");
        compute(cur);
        asm volatile("" ::: "memory");
        __builtin_amdgcn_s_barrier();
        cur ^= 1;
    }
    asm volatile("s_waitcnt vmcnt(0)" ::: "memory");
    __builtin_amdgcn_s_barrier();
    asm volatile("" ::: "memory");
    compute(cur);

    const int b = bh >> 3, n = bh & 7;
    unsigned short* Ab = At + ((size_t)b << 18);
    #pragma unroll
    for (int qf = 0; qf < 2; ++qf) {
        const float inv = 1.f / lacc[qf][0];
        const int qpos = q0 + qf * 16 + ln;
        #pragma unroll
        for (int df = 0; df < 2; ++df) {
            ushort4 pk;
            pk.x = f2bf(O_[df][qf][0] * inv);
            pk.y = f2bf(O_[df][qf][1] * inv);
            pk.z = f2bf(O_[df][qf][2] * inv);
            pk.w = f2bf(O_[df][qf][3] * inv);
            *(ushort4*)(Ab + (size_t)qpos * 256 + n * 32 + df * 16 + g * 4) = pk;
        }
    }
}

// ---------------------------------------------------------------------------
// Out GEMM via MFMA with register prefetch: out = Wo @ At^T + bias + x.
// ---------------------------------------------------------------------------
#define OUT_LOAD(WF, AF, KK)                                                        \
    {                                                                               \
        _Pragma("unroll") for (int df = 0; df < 2; ++df)                            \
            WF[df] = *(const bf16x8*)(Wo + (size_t)(ob + df * 16 + ln) * 256 + (KK) + g * 8); \
        _Pragma("unroll") for (int sf = 0; sf < 2; ++sf)                            \
            AF[sf] = *(const bf16x8*)(Ab + (size_t)(sb + sf * 16 + ln) * 256 + (KK) + g * 8); \
    }
#define OUT_MMA(WF, AF)                                                             \
    {                                                                               \
        _Pragma("unroll") for (int df = 0; df < 2; ++df)                            \
            _Pragma("unroll") for (int sf = 0; sf < 2; ++sf)                        \
                acc[df][sf] = __builtin_amdgcn_mfma_f32_16x16x32_bf16(WF[df], AF[sf], acc[df][sf], 0, 0, 0); \
    }

__global__ __launch_bounds__(256) void out_mfma(
    const unsigned short* __restrict__ Wo, const unsigned short* __restrict__ At,
    const float* __restrict__ bias, const float* __restrict__ x,
    float* __restrict__ out)
{
    const int tid = threadIdx.x;
    const int l = tid & 63, w = tid >> 6;
    const int g = l >> 4, ln = l & 15;
    const int b  = blockIdx.z;
    const int ob = blockIdx.y * 32;
    const int sb = blockIdx.x * 128 + w * 32;

    const unsigned short* Ab = At + ((size_t)b << 18);

    f32x4v acc[2][2];
    const f32x4v zero4 = {0.f, 0.f, 0.f, 0.f};
    #pragma unroll
    for (int df = 0; df < 2; ++df)
        #pragma unroll
        for (int sf = 0; sf < 2; ++sf) acc[df][sf] = zero4;

    bf16x8 wA[2], aA[2], wB[2], aB[2];
    OUT_LOAD(wA, aA, 0);
    #pragma unroll
    for (int k0 = 0; k0 < 256; k0 += 64) {
        if (k0 + 32 < 256) OUT_LOAD(wB, aB, k0 + 32);
        OUT_MMA(wA, aA);
        if (k0 + 64 < 256) OUT_LOAD(wA, aA, k0 + 64);
        OUT_MMA(wB, aB);
    }

    #pragma unroll
    for (int df = 0; df < 2; ++df) {
        const float4 b4 = *(const float4*)(bias + ob + df * 16 + g * 4);
        const float bias_r[4] = {b4.x, b4.y, b4.z, b4.w};
        #pragma unroll
        for (int sf = 0; sf < 2; ++sf) {
            const int s = sb + sf * 16 + ln;
            #pragma unroll
            for (int r = 0; r < 4; ++r) {
                const int o = ob + df * 16 + g * 4 + r;
                const size_t idx = ((size_t)b * CIN + o) * SSZ + s;
                out[idx] = acc[df][sf][r] + bias_r[r] + x[idx];
            }
        }
    }
}

// ---------------------------------------------------------------------------
extern "C" void kernel_launch(void* const* d_in, const int* in_sizes, int n_in,
                              void* d_out, int out_size, void* d_ws, size_t ws_size,
                              hipStream_t stream)
{
    const float* x     = (const float*)d_in[0];
    const float* w_qkv = (const float*)d_in[1];
    const float* b_qkv = (const float*)d_in[2];
    const float* w_out = (const float*)d_in[3];
    const float* b_out = (const float*)d_in[4];
    float* out = (float*)d_out;

    unsigned short* qkT   = (unsigned short*)d_ws;
    unsigned short* v_buf = qkT   + ((size_t)64 << 16);
    unsigned short* Xt    = v_buf + ((size_t)64 << 15);
    unsigned short* At    = Xt    + ((size_t)8 << 18);
    unsigned short* Wq    = At    + ((size_t)8 << 18);
    unsigned short* Wo    = Wq    + (size_t)768 * 256;

    prepass  <<<dim3(16, 4, 9),  256, 0, stream>>>(x, w_qkv, w_out, Xt, Wq, Wo);
    qkv_mfma <<<dim3(8, 12, 8),  256, 0, stream>>>(Wq, Xt, b_qkv, qkT, v_buf);
    attn_mfma<<<dim3(64, 8),     256, 0, stream>>>(qkT, v_buf, At);
    out_mfma <<<dim3(8, 8, 8),   256, 0, stream>>>(Wo, At, b_out, x, out);
}